// Round 26
// baseline (198.030 us; speedup 1.0000x reference)
//
#include <hip/hip_runtime.h>
#include <math.h>

#define B_ 4
#define S_ 2048
#define E_ 512
#define H_ 8
#define MLP_ 2048

typedef unsigned short u16;
typedef __attribute__((ext_vector_type(8))) short bf16x8;
typedef __attribute__((ext_vector_type(4))) float f32x4;

#define MFMA(a, b, c) __builtin_amdgcn_mfma_f32_16x16x32_bf16(a, b, c, 0, 0, 0)
// Q pre-scale: (1/8) * log2(e)  -> scores in log2 domain; hexp2 = bare v_exp_f32
#define QSCALE 0.18033688011112042f
#define hexp2(x) __builtin_amdgcn_exp2f(x)

__device__ __forceinline__ u16 f2bf(float f) {
  unsigned u = __builtin_bit_cast(unsigned, f);
  unsigned r = (u + 0x7FFFu + ((u >> 16) & 1u)) >> 16;
  return (u16)r;
}
// pack two f32 -> two bf16 in one instruction (lo = a, hi = b)
__device__ __forceinline__ unsigned cvtpk(float a, float b) {
  unsigned r;
  asm("v_cvt_pk_bf16_f32 %0, %1, %2" : "=v"(r) : "v"(a), "v"(b));
  return r;
}
__device__ __forceinline__ void gload_lds16(const void* g, void* l) {
  __builtin_amdgcn_global_load_lds(
      (const __attribute__((address_space(1))) unsigned int*)g,
      (__attribute__((address_space(3))) unsigned int*)l, 16, 0, 0);
}
// tanh-form GELU via hw exp2 + rcp: gelu(v) = v * sigmoid(2u), u = 0.79788456*(v + 0.044715 v^3)
__device__ __forceinline__ float gelu_fast(float v) {
  float u = v * (0.7978845608028654f + 0.03567740813636141f * v * v);
  float e = hexp2(u * -2.885390081777927f);   // exp(-2u) = exp2(-2u*log2e)
  return v * __builtin_amdgcn_rcpf(1.0f + e);
}

// ---------------- prep: 4 weight cvts + LN1, one launch ----------------
__global__ __launch_bounds__(256) void prep_k(const float* __restrict__ s0, u16* __restrict__ d0,
                                              const float* __restrict__ s1, u16* __restrict__ d1,
                                              const float* __restrict__ s2, u16* __restrict__ d2,
                                              const float* __restrict__ s3, u16* __restrict__ d3,
                                              const float* __restrict__ x, const float* __restrict__ g,
                                              const float* __restrict__ bta, u16* __restrict__ out) {
  int bid = blockIdx.x;
  if (bid < 3072) {
    const float* s; u16* d; int i;
    if (bid < 768)       { s = s0; d = d0; i = bid * 256 + threadIdx.x; }
    else if (bid < 1024) { s = s1; d = d1; i = (bid - 768) * 256 + threadIdx.x; }
    else if (bid < 2048) { s = s2; d = d2; i = (bid - 1024) * 256 + threadIdx.x; }
    else                 { s = s3; d = d3; i = (bid - 2048) * 256 + threadIdx.x; }
    float4 v = reinterpret_cast<const float4*>(s)[i];
    union { u16 u[4]; uint2 q; } p;
    p.u[0] = f2bf(v.x); p.u[1] = f2bf(v.y); p.u[2] = f2bf(v.z); p.u[3] = f2bf(v.w);
    reinterpret_cast<uint2*>(d)[i] = p.q;
    return;
  }
  int row = (bid - 3072) * 4 + (threadIdx.x >> 6);
  int l = threadIdx.x & 63;
  const float4* xr = reinterpret_cast<const float4*>(x + (size_t)row * 512);
  float4 a = xr[l], c = xr[l + 64];
  float s = a.x + a.y + a.z + a.w + c.x + c.y + c.z + c.w;
  float q = a.x*a.x + a.y*a.y + a.z*a.z + a.w*a.w + c.x*c.x + c.y*c.y + c.z*c.z + c.w*c.w;
  #pragma unroll
  for (int off = 32; off >= 1; off >>= 1) { s += __shfl_xor(s, off); q += __shfl_xor(q, off); }
  float mu = s * (1.0f / 512.0f);
  float var = q * (1.0f / 512.0f) - mu * mu;
  float rs = rsqrtf(var + 1e-5f);
  const float4* gv = reinterpret_cast<const float4*>(g);
  const float4* bv = reinterpret_cast<const float4*>(bta);
  #pragma unroll
  for (int half = 0; half < 2; ++half) {
    int idx = l + half * 64;
    float4 gg = gv[idx], bb = bv[idx];
    float4 vv = (half == 0) ? a : c;
    union { u16 u[4]; uint2 q2; } p;
    p.u[0] = f2bf((vv.x - mu) * rs * gg.x + bb.x);
    p.u[1] = f2bf((vv.y - mu) * rs * gg.y + bb.y);
    p.u[2] = f2bf((vv.z - mu) * rs * gg.z + bb.z);
    p.u[3] = f2bf((vv.w - mu) * rs * gg.w + bb.w);
    *reinterpret_cast<uint2*>(out + (size_t)row * 512 + idx * 4) = p.q2;
  }
}

// ---------------- LayerNorm (rows of 512) -> bf16 ----------------
__global__ __launch_bounds__(256) void ln_k(const float* __restrict__ x, const float* __restrict__ g,
                                            const float* __restrict__ bta, u16* __restrict__ out) {
  int row = blockIdx.x * 4 + (threadIdx.x >> 6);
  int l = threadIdx.x & 63;
  const float4* xr = reinterpret_cast<const float4*>(x + (size_t)row * 512);
  float4 a = xr[l], c = xr[l + 64];
  float s = a.x + a.y + a.z + a.w + c.x + c.y + c.z + c.w;
  float q = a.x*a.x + a.y*a.y + a.z*a.z + a.w*a.w + c.x*c.x + c.y*c.y + c.z*c.z + c.w*c.w;
  #pragma unroll
  for (int off = 32; off >= 1; off >>= 1) { s += __shfl_xor(s, off); q += __shfl_xor(q, off); }
  float mu = s * (1.0f / 512.0f);
  float var = q * (1.0f / 512.0f) - mu * mu;
  float rs = rsqrtf(var + 1e-5f);
  const float4* gv = reinterpret_cast<const float4*>(g);
  const float4* bv = reinterpret_cast<const float4*>(bta);
  #pragma unroll
  for (int half = 0; half < 2; ++half) {
    int idx = l + half * 64;
    float4 gg = gv[idx], bb = bv[idx];
    float4 vv = (half == 0) ? a : c;
    union { u16 u[4]; uint2 q2; } p;
    p.u[0] = f2bf((vv.x - mu) * rs * gg.x + bb.x);
    p.u[1] = f2bf((vv.y - mu) * rs * gg.y + bb.y);
    p.u[2] = f2bf((vv.z - mu) * rs * gg.z + bb.z);
    p.u[3] = f2bf((vv.w - mu) * rs * gg.w + bb.w);
    *reinterpret_cast<uint2*>(out + (size_t)row * 512 + idx * 4) = p.q2;
  }
}

// ---------------- GEMM (BM=128, BN=128, BK=32 DOUBLE-BUFFERED, XCD-swizzled grid) --------
// Same 32KB LDS as the old BK=64 single-buffer; staging latency hidden by dbuf.
// 64B rows: swizzle group = hi ^ ((row>>1)&3) -> 8 distinct 4-bank slots / 16 lanes (free).
// EPI 0: -> bf16   EPI 1: + resid(f32) -> f32   EPI 2: gelu -> bf16
// EPI 3: QKV: Q*QSCALE -> qkv; K -> qkv; V -> vT[b][h][d][k'] where k' matches the
//        in-register PA k-slot order of the swapped-QK^T fctx:
//        kin=(j:2|hi:2|r:2) -> pos = (j>>1)*32 + hi*8 + (j&1)*4 + r  (bijective)
template <int EPI>
__global__ __launch_bounds__(256) void gemm_nt(const u16* __restrict__ A, const u16* __restrict__ Bw,
                                               const float* __restrict__ bias,
                                               const float* __restrict__ resid,
                                               void* __restrict__ Cout, u16* __restrict__ vTout,
                                               int M, int N, int K) {
  __shared__ u16 lA[2][128 * 32];
  __shared__ u16 lB[2][128 * 32];
  int t = threadIdx.x, w = t >> 6, l = t & 63;
  // XCD-aware remap: HW ids round-robin XCDs; give each XCD a contiguous logical chunk.
  int orig = blockIdx.y * gridDim.x + blockIdx.x;
  int cpx = (gridDim.x * gridDim.y) >> 3;
  int swz = (orig & 7) * cpx + (orig >> 3);
  int m0 = (swz / gridDim.x) * 128, n0 = (swz % gridDim.x) * 128;
  int wr = w >> 1, wc = w & 1;
  int rl = l & 15, hi = l >> 4;
  f32x4 zero = {0.f, 0.f, 0.f, 0.f};
  f32x4 acc[4][4];
  #pragma unroll
  for (int mi = 0; mi < 4; ++mi)
    #pragma unroll
    for (int ni = 0; ni < 4; ++ni) acc[mi][ni] = zero;

  // stage K-tile 0
  #pragma unroll
  for (int it = 0; it < 2; ++it) {
    int cid = it * 256 + t;
    int row = cid >> 2, g = cid & 3;
    int gs = (g ^ ((row >> 1) & 3)) * 8;
    gload_lds16(A + (size_t)(m0 + row) * K + gs, &lA[0][(size_t)cid * 8]);
    gload_lds16(Bw + (size_t)(n0 + row) * K + gs, &lB[0][(size_t)cid * 8]);
  }
  __syncthreads();
  int nk = K >> 5;
  for (int kt = 0; kt < nk; ++kt) {
    int cur = kt & 1;
    // prefetch next K-tile first (buf[cur^1] free since previous barrier)
    if (kt + 1 < nk) {
      int k0 = (kt + 1) << 5;
      #pragma unroll
      for (int it = 0; it < 2; ++it) {
        int cid = it * 256 + t;
        int row = cid >> 2, g = cid & 3;
        int gs = (g ^ ((row >> 1) & 3)) * 8;
        gload_lds16(A + (size_t)(m0 + row) * K + k0 + gs, &lA[cur ^ 1][(size_t)cid * 8]);
        gload_lds16(Bw + (size_t)(n0 + row) * K + k0 + gs, &lB[cur ^ 1][(size_t)cid * 8]);
      }
    }
    bf16x8 af[4], bfr[4];
    #pragma unroll
    for (int mi = 0; mi < 4; ++mi) {
      int row = wr * 64 + mi * 16 + rl;
      af[mi] = *reinterpret_cast<const bf16x8*>(&lA[cur][row * 32 + ((hi ^ ((row >> 1) & 3)) * 8)]);
    }
    #pragma unroll
    for (int ni = 0; ni < 4; ++ni) {
      int row = wc * 64 + ni * 16 + rl;
      bfr[ni] = *reinterpret_cast<const bf16x8*>(&lB[cur][row * 32 + ((hi ^ ((row >> 1) & 3)) * 8)]);
    }
    #pragma unroll
    for (int mi = 0; mi < 4; ++mi)
      #pragma unroll
      for (int ni = 0; ni < 4; ++ni) acc[mi][ni] = MFMA(af[mi], bfr[ni], acc[mi][ni]);
    __syncthreads();   // drains prefetch + protects buffer reuse
  }
  int rg = hi * 4;
  #pragma unroll
  for (int mi = 0; mi < 4; ++mi) {
    #pragma unroll
    for (int ni = 0; ni < 4; ++ni) {
      int gn = n0 + wc * 64 + ni * 16 + rl;
      float bvv = bias[gn];
      #pragma unroll
      for (int r = 0; r < 4; ++r) {
        int gm = m0 + wr * 64 + mi * 16 + rg + r;
        size_t off = (size_t)gm * N + gn;
        float v = acc[mi][ni][r] + bvv;
        if (EPI == 0) {
          ((u16*)Cout)[off] = f2bf(v);
        } else if (EPI == 1) {
          ((float*)Cout)[off] = v + resid[off];
        } else if (EPI == 2) {
          ((u16*)Cout)[off] = f2bf(gelu_fast(v));
        } else {
          int key = gm & 2047, bb = gm >> 11;
          if (gn < 512) {
            ((u16*)Cout)[off] = f2bf(v * QSCALE);
          } else if (gn < 1024) {
            ((u16*)Cout)[off] = f2bf(v);
          } else {
            int d = gn - 1024;             // h*64 + dim
            int kin = key & 63;
            int pc = (key & ~63) +
                     (((kin >> 5) << 5) | (((kin >> 2) & 3) << 3) | (((kin >> 4) & 1) << 2) | (kin & 3));
            vTout[((size_t)(bb * 8 + (d >> 6)) * 64 + (d & 63)) * 2048 + pc] = f2bf(v);
          }
        }
      }
    }
  }
}

// ---------------- GEMM narrow-N (BM=128, BN=64, BK=64, DOUBLE-BUFFERED) ----------------
// EPI 1 only: + resid(f32) -> f32. Top-of-loop prefetch; one barrier per K-iter.
__global__ __launch_bounds__(256) void gemm_n64_k(const u16* __restrict__ A, const u16* __restrict__ Bw,
                                                  const float* __restrict__ bias,
                                                  const float* __restrict__ resid,
                                                  float* __restrict__ Cout,
                                                  int M, int N, int K) {
  __shared__ u16 lA[2][128 * 64];
  __shared__ u16 lB[2][64 * 64];
  int t = threadIdx.x, w = t >> 6, l = t & 63;
  int orig = blockIdx.y * gridDim.x + blockIdx.x;
  int cpx = (gridDim.x * gridDim.y) >> 3;
  int swz = (orig & 7) * cpx + (orig >> 3);
  int m0 = (swz / gridDim.x) * 128, n0 = (swz % gridDim.x) * 64;
  int wr = w >> 1, wc = w & 1;          // waves: 2 in M (64 rows each) x 2 in N (32 cols each)
  int rl = l & 15, hi = l >> 4;
  f32x4 zero = {0.f, 0.f, 0.f, 0.f};
  f32x4 acc[4][2];
  #pragma unroll
  for (int mi = 0; mi < 4; ++mi)
    #pragma unroll
    for (int ni = 0; ni < 2; ++ni) acc[mi][ni] = zero;

  // stage tile 0
  #pragma unroll
  for (int it = 0; it < 4; ++it) {
    int cid = it * 256 + t;
    int row = cid >> 3, g = cid & 7;
    int gs = (g ^ (row & 7)) * 8;
    gload_lds16(A + (size_t)(m0 + row) * K + gs, &lA[0][(size_t)cid * 8]);
  }
  #pragma unroll
  for (int it = 0; it < 2; ++it) {
    int cid = it * 256 + t;
    int row = cid >> 3, g = cid & 7;
    int gs = (g ^ (row & 7)) * 8;
    gload_lds16(Bw + (size_t)(n0 + row) * K + gs, &lB[0][(size_t)cid * 8]);
  }
  __syncthreads();
  int nk = K >> 6;
  for (int kt = 0; kt < nk; ++kt) {
    int cur = kt & 1;
    // prefetch next K-tile first (buf[cur^1] free since previous barrier)
    if (kt + 1 < nk) {
      int k0 = (kt + 1) << 6;
      #pragma unroll
      for (int it = 0; it < 4; ++it) {
        int cid = it * 256 + t;
        int row = cid >> 3, g = cid & 7;
        int gs = (g ^ (row & 7)) * 8;
        gload_lds16(A + (size_t)(m0 + row) * K + k0 + gs, &lA[cur ^ 1][(size_t)cid * 8]);
      }
      #pragma unroll
      for (int it = 0; it < 2; ++it) {
        int cid = it * 256 + t;
        int row = cid >> 3, g = cid & 7;
        int gs = (g ^ (row & 7)) * 8;
        gload_lds16(Bw + (size_t)(n0 + row) * K + k0 + gs, &lB[cur ^ 1][(size_t)cid * 8]);
      }
    }
    #pragma unroll
    for (int kk = 0; kk < 2; ++kk) {
      bf16x8 af[4], bfr[2];
      #pragma unroll
      for (int mi = 0; mi < 4; ++mi) {
        int row = wr * 64 + mi * 16 + rl;
        af[mi] = *reinterpret_cast<const bf16x8*>(&lA[cur][row * 64 + (((kk * 4 + hi) ^ (row & 7)) * 8)]);
      }
      #pragma unroll
      for (int ni = 0; ni < 2; ++ni) {
        int row = wc * 32 + ni * 16 + rl;
        bfr[ni] = *reinterpret_cast<const bf16x8*>(&lB[cur][row * 64 + (((kk * 4 + hi) ^ (row & 7)) * 8)]);
      }
      #pragma unroll
      for (int mi = 0; mi < 4; ++mi)
        #pragma unroll
        for (int ni = 0; ni < 2; ++ni) acc[mi][ni] = MFMA(af[mi], bfr[ni], acc[mi][ni]);
    }
    __syncthreads();   // drains prefetch + protects buffer reuse
  }
  int rg = hi * 4;
  #pragma unroll
  for (int mi = 0; mi < 4; ++mi) {
    #pragma unroll
    for (int ni = 0; ni < 2; ++ni) {
      int gn = n0 + wc * 32 + ni * 16 + rl;
      float bvv = bias[gn];
      #pragma unroll
      for (int r = 0; r < 4; ++r) {
        int gm = m0 + wr * 64 + mi * 16 + rg + r;
        size_t off = (size_t)gm * N + gn;
        Cout[off] = acc[mi][ni][r] + bvv + resid[off];
      }
    }
  }
}

// ---------------- Fused flash ctx v8: swapped QK^T, P fully in registers ----------------
__global__ __launch_bounds__(512) void attn_fctx8_k(const u16* __restrict__ qkv,
                                                    const u16* __restrict__ vT,
                                                    float* __restrict__ rinv,
                                                    u16* __restrict__ ctx) {
  __shared__ u16 kbuf[2][64 * 64];
  __shared__ u16 vbuf[2][64 * 64];
  int t = threadIdx.x, w = t >> 6, l = t & 63;
  // HW linear id (x fastest); xcd = n&7. Group (b,h): 32 groups x 16 q-blocks.
  int n = blockIdx.x + 16 * (blockIdx.y + 8 * blockIdx.z);
  int slot = n >> 3;
  int g = (n & 7) * 4 + (slot >> 4);
  int qb = slot & 15;
  int h = g >> 2, b = g & 3;
  int qt = qb * 128 + w * 16;
  int rl = l & 15, hi = l >> 4;
  f32x4 zero = {0.f, 0.f, 0.f, 0.f};
  // Q as B-frag: lane (hi,rl) holds Q[q=rl][d = hi*8+e] (+32 for second half)
  bf16x8 q0 = *reinterpret_cast<const bf16x8*>(
      qkv + (size_t)(b * S_ + qt + rl) * 1536 + h * 64 + hi * 8);
  bf16x8 q1 = *reinterpret_cast<const bf16x8*>(
      qkv + (size_t)(b * S_ + qt + rl) * 1536 + h * 64 + 32 + hi * 8);
  f32x4 acc[4];
  float lspq = 0.f;   // per-lane partial row-sum for q = rl
  #pragma unroll
  for (int dc = 0; dc < 4; ++dc) acc[dc] = zero;
  // stage tile 0 (512 threads x 16B cover each 8KB tile)
  {
    int r = t >> 3, gp = t & 7, gl = gp ^ (r & 7);
    gload_lds16(qkv + (size_t)(b * S_ + r) * 1536 + 512 + h * 64 + gl * 8, &kbuf[0][t * 8]);
    gload_lds16(vT + ((size_t)(b * H_ + h) * 64 + r) * 2048 + gl * 8, &vbuf[0][t * 8]);
  }
  __syncthreads();
  for (int kt = 0; kt < 32; ++kt) {
    int cur = kt & 1;
    if (kt + 1 < 32) {
      int r = t >> 3, gp = t & 7, gl = gp ^ (r & 7);
      gload_lds16(qkv + (size_t)(b * S_ + (kt + 1) * 64 + r) * 1536 + 512 + h * 64 + gl * 8,
                  &kbuf[cur ^ 1][t * 8]);
      gload_lds16(vT + ((size_t)(b * H_ + h) * 64 + r) * 2048 + (kt + 1) * 64 + gl * 8,
                  &vbuf[cur ^ 1][t * 8]);
    }
    const u16* kb = kbuf[cur];
    const u16* vb = vbuf[cur];
    // QK^T swapped: lane holds S[key=j*16+hi*4+r][q=rl]
    f32x4 s[4];
    __builtin_amdgcn_s_setprio(1);
    #pragma unroll
    for (int j = 0; j < 4; ++j) {
      int row = j * 16 + rl;
      bf16x8 k0 = *reinterpret_cast<const bf16x8*>(kb + row * 64 + ((hi ^ (row & 7)) * 8));
      bf16x8 k1 = *reinterpret_cast<const bf16x8*>(kb + row * 64 + (((hi + 4) ^ (row & 7)) * 8));
      s[j] = MFMA(k0, q0, zero);
      s[j] = MFMA(k1, q1, s[j]);
    }
    __builtin_amdgcn_s_setprio(0);
    // p = exp2(s); build PA frags in-register (k-slot order matches vT permutation)
    float p[4][4];
    #pragma unroll
    for (int j = 0; j < 4; ++j)
      #pragma unroll
      for (int r = 0; r < 4; ++r) {
        p[j][r] = hexp2(s[j][r]);
        lspq += p[j][r];
      }
    union { unsigned u[4]; bf16x8 v; } pa0, pa1;
    pa0.u[0] = cvtpk(p[0][0], p[0][1]); pa0.u[1] = cvtpk(p[0][2], p[0][3]);
    pa0.u[2] = cvtpk(p[1][0], p[1][1]); pa0.u[3] = cvtpk(p[1][2], p[1][3]);
    pa1.u[0] = cvtpk(p[2][0], p[2][1]); pa1.u[1] = cvtpk(p[2][2], p[2][3]);
    pa1.u[2] = cvtpk(p[3][0], p[3][1]); pa1.u[3] = cvtpk(p[3][2], p[3][3]);
    // PV: register A-operand
    __builtin_amdgcn_s_setprio(1);
    #pragma unroll
    for (int dc = 0; dc < 4; ++dc) {
      int row = dc * 16 + rl;
      bf16x8 v0 = *reinterpret_cast<const bf16x8*>(vb + row * 64 + ((hi ^ (row & 7)) * 8));
      bf16x8 v1 = *reinterpret_cast<const bf16x8*>(vb + row * 64 + (((hi + 4) ^ (row & 7)) * 8));
      acc[dc] = MFMA(pa0.v, v0, acc[dc]);
      acc[dc] = MFMA(pa1.v, v1, acc[dc]);
    }
    __builtin_amdgcn_s_setprio(0);
    __syncthreads();
  }
  // finish row sums: reduce over the 4 hi-groups
  lspq += __shfl_xor(lspq, 16);
  lspq += __shfl_xor(lspq, 32);
  float lr[4];
  #pragma unroll
  for (int r = 0; r < 4; ++r) lr[r] = __shfl(lspq, hi * 4 + r);
  #pragma unroll
  for (int dc = 0; dc < 4; ++dc)
    #pragma unroll
    for (int r = 0; r < 4; ++r)
      ctx[(size_t)(b * S_ + qt + hi * 4 + r) * 512 + h * 64 + dc * 16 + rl] =
          f2bf(acc[dc][r] / lr[r]);
  if (l < 16)
    rinv[(size_t)(b * H_ + h) * S_ + qt + rl] = 0.125f / lspq;
}

// ---------------- head-mean probs v10: dbuf heads, TOP-of-loop prefetch (linear IDs) ----------------
__global__ __launch_bounds__(256) void attn_mean10_k(const u16* __restrict__ qkv,
                                                     const float* __restrict__ rinv,
                                                     float* __restrict__ attn) {
  __shared__ u16 lQ[2][128 * 64];
  __shared__ u16 lK[2][128 * 64];
  int t = threadIdx.x, w = t >> 6, l = t & 63;
  int kt = blockIdx.x, qt = blockIdx.y, b = blockIdx.z;
  int wr = w >> 1, wc = w & 1;
  int rl = l & 15, hi = l >> 4;
  f32x4 zero = {0.f, 0.f, 0.f, 0.f};
  f32x4 acc[4][4];
  #pragma unroll
  for (int mi = 0; mi < 4; ++mi)
    #pragma unroll
    for (int ni = 0; ni < 4; ++ni) acc[mi][ni] = zero;

  const u16* qbase = qkv + (size_t)(b * S_ + qt * 128) * 1536;
  const u16* kbase = qkv + (size_t)(b * S_ + kt * 128) * 1536 + 512;
  // stage head 0 into buffer 0
  #pragma unroll
  for (int it = 0; it < 4; ++it) {
    int cid = it * 256 + t;
    int row = cid >> 3, g = cid & 7;
    int gs = (g ^ (row & 7)) * 8;
    gload_lds16(qbase + (size_t)row * 1536 + gs, &lQ[0][cid * 8]);
    gload_lds16(kbase + (size_t)row * 1536 + gs, &lK[0][cid * 8]);
  }
  __syncthreads();
  for (int h = 0; h < 8; ++h) {
    int cur = h & 1;
    // issue next head's staging FIRST (buf[cur^1] free since previous barrier)
    if (h + 1 < 8) {
      #pragma unroll
      for (int it = 0; it < 4; ++it) {
        int cid = it * 256 + t;
        int row = cid >> 3, g = cid & 7;
        int gs = (g ^ (row & 7)) * 8;
        gload_lds16(qbase + (size_t)row * 1536 + (h + 1) * 64 + gs, &lQ[cur ^ 1][cid * 8]);
        gload_lds16(kbase + (size_t)row * 1536 + (h + 1) * 64 + gs, &lK[cur ^ 1][cid * 8]);
      }
    }
    float4 rv[4];
    #pragma unroll
    for (int mi = 0; mi < 4; ++mi)
      rv[mi] = *reinterpret_cast<const float4*>(
          rinv + (size_t)(b * H_ + h) * S_ + qt * 128 + wr * 64 + mi * 16 + hi * 4);
    f32x4 s[4][4];
    __builtin_amdgcn_s_setprio(1);
    #pragma unroll
    for (int kk = 0; kk < 2; ++kk) {
      bf16x8 af[4], bfr[4];
      #pragma unroll
      for (int mi = 0; mi < 4; ++mi) {
        int row = wr * 64 + mi * 16 + rl;
        af[mi] = *reinterpret_cast<const bf16x8*>(&lQ[cur][row * 64 + (((kk * 4 + hi) ^ (row & 7)) * 8)]);
      }
      #pragma unroll
      for (int ni = 0; ni < 4; ++ni) {
        int row = wc * 64 + ni * 16 + rl;
        bfr[ni] = *reinterpret_cast<const bf16x8*>(&lK[cur][row * 64 + (((kk * 4 + hi) ^ (row & 7)) * 8)]);
      }
      #pragma unroll
      for (int mi = 0; mi < 4; ++mi)
        #pragma unroll
        for (int ni = 0; ni < 4; ++ni)
          s[mi][ni] = (kk == 0) ? MFMA(af[mi], bfr[ni], zero) : MFMA(af[mi], bfr[ni], s[mi][ni]);
    }
    __builtin_amdgcn_s_setprio(0);
    #pragma unroll
    for (int mi = 0; mi < 4; ++mi) {
      float rva[4] = {rv[mi].x, rv[mi].y, rv[mi].z, rv[mi].w};
      #pragma unroll
      for (int ni = 0; ni < 4; ++ni)
        #pragma unroll
        for (int r = 0; r < 4; ++r)
          acc[mi][ni][r] += hexp2(s[mi][ni][r]) * rva[r];
    }
    __syncthreads();   // drains prefetch vmcnt; protects buffer reuse
  }
  #pragma unroll
  for (int mi = 0; mi < 4; ++mi)
    #pragma unroll
    for (int r = 0; r < 4; ++r) {
      size_t rowoff = (size_t)(b * S_ + qt * 128 + wr * 64 + mi * 16 + hi * 4 + r) * 2048 +
                      kt * 128 + wc * 64 + rl;
      #pragma unroll
      for (int ni = 0; ni < 4; ++ni)
        attn[rowoff + ni * 16] = acc[mi][ni][r];
    }
}

// ---------------- launcher ----------------
extern "C" void kernel_launch(void* const* d_in, const int* in_sizes, int n_in,
                              void* d_out, int out_size, void* d_ws, size_t ws_size,
                              hipStream_t stream) {
  const float* query     = (const float*)d_in[0];
  const float* ln1_g     = (const float*)d_in[1];
  const float* ln1_b     = (const float*)d_in[2];
  const float* in_proj_w = (const float*)d_in[3];
  const float* in_proj_b = (const float*)d_in[4];
  const float* out_w     = (const float*)d_in[5];
  const float* out_b     = (const float*)d_in[6];
  const float* ln2_g     = (const float*)d_in[7];
  const float* ln2_b     = (const float*)d_in[8];
  const float* w1        = (const float*)d_in[9];
  const float* b1        = (const float*)d_in[10];
  const float* w2        = (const float*)d_in[11];
  const float* b2        = (const float*)d_in[12];

  u16* ws = (u16*)d_ws;
  u16* wq_bf = ws;                       // [1536,512]
  u16* wo_bf = wq_bf + 1536 * 512;       // [512,512]
  u16* w1_bf = wo_bf + 512 * 512;        // [2048,512]
  u16* w2_bf = w1_bf + 2048 * 512;       // [512,2048]
  u16* xq_bf = w2_bf + 512 * 2048;       // [8192,512]
  u16* qkv_bf = xq_bf + 8192 * 512;      // [8192,1536] (V section unused)
  u16* ctx_bf = qkv_bf + 8192 * 1536;    // [8192,512]
  u16* h_bf   = ctx_bf + 8192 * 512;     // [8192,512]
  u16* mh_bf  = h_bf + 8192 * 512;       // [8192,2048]
  float* rinv = (float*)(mh_bf + 8192 * 2048);  // [B*H*S]
  u16* vT = mh_bf;                       // [4,8,64,2048] alias (mh dead until MLP1)

  float* xout = (float*)d_out;                    // [8192,512]
  float* attn = xout + (size_t)8192 * 512;        // [4,2048,2048]

  // 1. weights -> bf16 + LN1 (single fused launch)
  prep_k<<<5120, 256, 0, stream>>>(in_proj_w, wq_bf, out_w, wo_bf, w1, w1_bf, w2, w2_bf,
                                   query, ln1_g, ln1_b, xq_bf);

  // 2. QKV projection (Q pre-scaled by log2e/8; V transposed+PA-permuted to vT)  [BK=32 dbuf]
  gemm_nt<3><<<dim3(12, 64), 256, 0, stream>>>(xq_bf, wq_bf, in_proj_b, nullptr, qkv_bf, vT, 8192, 1536, 512);

  // 3. fused flash ctx (swapped QK^T, register P, XCD-affinity remap)
  attn_fctx8_k<<<dim3(16, 8, 4), 512, 0, stream>>>(qkv_bf, vT, rinv, ctx_bf);

  // 4. head-mean probs -> attn_weight output (dbuf heads, linear IDs)
  attn_mean10_k<<<dim3(16, 16, 4), 256, 0, stream>>>(qkv_bf, rinv, attn);

  // 5. out-proj + residual(query) -> x (f32, d_out)  [BN=64, dbuf]
  gemm_n64_k<<<dim3(8, 64), 256, 0, stream>>>(ctx_bf, wo_bf, out_b, query, xout, 8192, 512, 512);

  // 6. LN2 on x
  ln_k<<<2048, 256, 0, stream>>>(xout, ln2_g, ln2_b, h_bf);

  // 7. MLP up + GELU (tanh-form via hw exp2)  [BK=32 dbuf]
  gemm_nt<2><<<dim3(16, 64), 256, 0, stream>>>(h_bf, w1_bf, b1, nullptr, mh_bf, nullptr, 8192, 2048, 512);

  // 8. MLP down + residual(x) -> final x (in-place)  [BN=64, dbuf]
  gemm_n64_k<<<dim3(8, 64), 256, 0, stream>>>(mh_bf, w2_bf, b2, xout, xout, 8192, 512, 2048);
}

// Round 27
// 195.873 us; speedup vs baseline: 1.0110x; 1.0110x over previous
//
#include <hip/hip_runtime.h>
#include <math.h>

#define B_ 4
#define S_ 2048
#define E_ 512
#define H_ 8
#define MLP_ 2048

typedef unsigned short u16;
typedef __attribute__((ext_vector_type(8))) short bf16x8;
typedef __attribute__((ext_vector_type(4))) float f32x4;

#define MFMA(a, b, c) __builtin_amdgcn_mfma_f32_16x16x32_bf16(a, b, c, 0, 0, 0)
// Q pre-scale: (1/8) * log2(e)  -> scores in log2 domain; hexp2 = bare v_exp_f32
#define QSCALE 0.18033688011112042f
#define hexp2(x) __builtin_amdgcn_exp2f(x)

__device__ __forceinline__ u16 f2bf(float f) {
  unsigned u = __builtin_bit_cast(unsigned, f);
  unsigned r = (u + 0x7FFFu + ((u >> 16) & 1u)) >> 16;
  return (u16)r;
}
// pack two f32 -> two bf16 in one instruction (lo = a, hi = b)
__device__ __forceinline__ unsigned cvtpk(float a, float b) {
  unsigned r;
  asm("v_cvt_pk_bf16_f32 %0, %1, %2" : "=v"(r) : "v"(a), "v"(b));
  return r;
}
__device__ __forceinline__ void gload_lds16(const void* g, void* l) {
  __builtin_amdgcn_global_load_lds(
      (const __attribute__((address_space(1))) unsigned int*)g,
      (__attribute__((address_space(3))) unsigned int*)l, 16, 0, 0);
}
// tanh-form GELU via hw exp2 + rcp: gelu(v) = v * sigmoid(2u), u = 0.79788456*(v + 0.044715 v^3)
__device__ __forceinline__ float gelu_fast(float v) {
  float u = v * (0.7978845608028654f + 0.03567740813636141f * v * v);
  float e = hexp2(u * -2.885390081777927f);   // exp(-2u) = exp2(-2u*log2e)
  return v * __builtin_amdgcn_rcpf(1.0f + e);
}

// ---------------- prep: 4 weight cvts + LN1, one launch ----------------
__global__ __launch_bounds__(256) void prep_k(const float* __restrict__ s0, u16* __restrict__ d0,
                                              const float* __restrict__ s1, u16* __restrict__ d1,
                                              const float* __restrict__ s2, u16* __restrict__ d2,
                                              const float* __restrict__ s3, u16* __restrict__ d3,
                                              const float* __restrict__ x, const float* __restrict__ g,
                                              const float* __restrict__ bta, u16* __restrict__ out) {
  int bid = blockIdx.x;
  if (bid < 3072) {
    const float* s; u16* d; int i;
    if (bid < 768)       { s = s0; d = d0; i = bid * 256 + threadIdx.x; }
    else if (bid < 1024) { s = s1; d = d1; i = (bid - 768) * 256 + threadIdx.x; }
    else if (bid < 2048) { s = s2; d = d2; i = (bid - 1024) * 256 + threadIdx.x; }
    else                 { s = s3; d = d3; i = (bid - 2048) * 256 + threadIdx.x; }
    float4 v = reinterpret_cast<const float4*>(s)[i];
    union { u16 u[4]; uint2 q; } p;
    p.u[0] = f2bf(v.x); p.u[1] = f2bf(v.y); p.u[2] = f2bf(v.z); p.u[3] = f2bf(v.w);
    reinterpret_cast<uint2*>(d)[i] = p.q;
    return;
  }
  int row = (bid - 3072) * 4 + (threadIdx.x >> 6);
  int l = threadIdx.x & 63;
  const float4* xr = reinterpret_cast<const float4*>(x + (size_t)row * 512);
  float4 a = xr[l], c = xr[l + 64];
  float s = a.x + a.y + a.z + a.w + c.x + c.y + c.z + c.w;
  float q = a.x*a.x + a.y*a.y + a.z*a.z + a.w*a.w + c.x*c.x + c.y*c.y + c.z*c.z + c.w*c.w;
  #pragma unroll
  for (int off = 32; off >= 1; off >>= 1) { s += __shfl_xor(s, off); q += __shfl_xor(q, off); }
  float mu = s * (1.0f / 512.0f);
  float var = q * (1.0f / 512.0f) - mu * mu;
  float rs = rsqrtf(var + 1e-5f);
  const float4* gv = reinterpret_cast<const float4*>(g);
  const float4* bv = reinterpret_cast<const float4*>(bta);
  #pragma unroll
  for (int half = 0; half < 2; ++half) {
    int idx = l + half * 64;
    float4 gg = gv[idx], bb = bv[idx];
    float4 vv = (half == 0) ? a : c;
    union { u16 u[4]; uint2 q2; } p;
    p.u[0] = f2bf((vv.x - mu) * rs * gg.x + bb.x);
    p.u[1] = f2bf((vv.y - mu) * rs * gg.y + bb.y);
    p.u[2] = f2bf((vv.z - mu) * rs * gg.z + bb.z);
    p.u[3] = f2bf((vv.w - mu) * rs * gg.w + bb.w);
    *reinterpret_cast<uint2*>(out + (size_t)row * 512 + idx * 4) = p.q2;
  }
}

// ---------------- LayerNorm (rows of 512) -> bf16 ----------------
__global__ __launch_bounds__(256) void ln_k(const float* __restrict__ x, const float* __restrict__ g,
                                            const float* __restrict__ bta, u16* __restrict__ out) {
  int row = blockIdx.x * 4 + (threadIdx.x >> 6);
  int l = threadIdx.x & 63;
  const float4* xr = reinterpret_cast<const float4*>(x + (size_t)row * 512);
  float4 a = xr[l], c = xr[l + 64];
  float s = a.x + a.y + a.z + a.w + c.x + c.y + c.z + c.w;
  float q = a.x*a.x + a.y*a.y + a.z*a.z + a.w*a.w + c.x*c.x + c.y*c.y + c.z*c.z + c.w*c.w;
  #pragma unroll
  for (int off = 32; off >= 1; off >>= 1) { s += __shfl_xor(s, off); q += __shfl_xor(q, off); }
  float mu = s * (1.0f / 512.0f);
  float var = q * (1.0f / 512.0f) - mu * mu;
  float rs = rsqrtf(var + 1e-5f);
  const float4* gv = reinterpret_cast<const float4*>(g);
  const float4* bv = reinterpret_cast<const float4*>(bta);
  #pragma unroll
  for (int half = 0; half < 2; ++half) {
    int idx = l + half * 64;
    float4 gg = gv[idx], bb = bv[idx];
    float4 vv = (half == 0) ? a : c;
    union { u16 u[4]; uint2 q2; } p;
    p.u[0] = f2bf((vv.x - mu) * rs * gg.x + bb.x);
    p.u[1] = f2bf((vv.y - mu) * rs * gg.y + bb.y);
    p.u[2] = f2bf((vv.z - mu) * rs * gg.z + bb.z);
    p.u[3] = f2bf((vv.w - mu) * rs * gg.w + bb.w);
    *reinterpret_cast<uint2*>(out + (size_t)row * 512 + idx * 4) = p.q2;
  }
}

// ---------------- GEMM (BM=128, BN=128, BK=64, swizzled LDS, XCD-swizzled grid) ----------
// EPI 0: -> bf16   EPI 1: + resid(f32) -> f32   EPI 2: gelu -> bf16
// EPI 3: QKV: Q*QSCALE -> qkv; K -> qkv; V -> vT[b][h][d][k'] where k' matches the
//        in-register PA k-slot order of the swapped-QK^T fctx:
//        kin=(j:2|hi:2|r:2) -> pos = (j>>1)*32 + hi*8 + (j&1)*4 + r  (bijective)
template <int EPI>
__global__ __launch_bounds__(256) void gemm_nt(const u16* __restrict__ A, const u16* __restrict__ Bw,
                                               const float* __restrict__ bias,
                                               const float* __restrict__ resid,
                                               void* __restrict__ Cout, u16* __restrict__ vTout,
                                               int M, int N, int K) {
  __shared__ u16 lA[128 * 64];
  __shared__ u16 lB[128 * 64];
  int t = threadIdx.x, w = t >> 6, l = t & 63;
  // XCD-aware remap: HW ids round-robin XCDs; give each XCD a contiguous logical chunk.
  int orig = blockIdx.y * gridDim.x + blockIdx.x;
  int cpx = (gridDim.x * gridDim.y) >> 3;
  int swz = (orig & 7) * cpx + (orig >> 3);
  int m0 = (swz / gridDim.x) * 128, n0 = (swz % gridDim.x) * 128;
  int wr = w >> 1, wc = w & 1;
  int rl = l & 15, hi = l >> 4;
  f32x4 zero = {0.f, 0.f, 0.f, 0.f};
  f32x4 acc[4][4];
  #pragma unroll
  for (int mi = 0; mi < 4; ++mi)
    #pragma unroll
    for (int ni = 0; ni < 4; ++ni) acc[mi][ni] = zero;

  for (int k0 = 0; k0 < K; k0 += 64) {
    #pragma unroll
    for (int it = 0; it < 4; ++it) {
      int cid = it * 256 + t;
      int row = cid >> 3, g = cid & 7;
      int gs = (g ^ (row & 7)) * 8;
      gload_lds16(A + (size_t)(m0 + row) * K + k0 + gs, lA + (size_t)cid * 8);
      gload_lds16(Bw + (size_t)(n0 + row) * K + k0 + gs, lB + (size_t)cid * 8);
    }
    __syncthreads();
    #pragma unroll
    for (int kk = 0; kk < 2; ++kk) {
      bf16x8 af[4], bfr[4];
      #pragma unroll
      for (int mi = 0; mi < 4; ++mi) {
        int row = wr * 64 + mi * 16 + rl;
        af[mi] = *reinterpret_cast<const bf16x8*>(&lA[row * 64 + (((kk * 4 + hi) ^ (row & 7)) * 8)]);
      }
      #pragma unroll
      for (int ni = 0; ni < 4; ++ni) {
        int row = wc * 64 + ni * 16 + rl;
        bfr[ni] = *reinterpret_cast<const bf16x8*>(&lB[row * 64 + (((kk * 4 + hi) ^ (row & 7)) * 8)]);
      }
      #pragma unroll
      for (int mi = 0; mi < 4; ++mi)
        #pragma unroll
        for (int ni = 0; ni < 4; ++ni) acc[mi][ni] = MFMA(af[mi], bfr[ni], acc[mi][ni]);
    }
    __syncthreads();
  }
  int rg = hi * 4;
  #pragma unroll
  for (int mi = 0; mi < 4; ++mi) {
    #pragma unroll
    for (int ni = 0; ni < 4; ++ni) {
      int gn = n0 + wc * 64 + ni * 16 + rl;
      float bvv = bias[gn];
      #pragma unroll
      for (int r = 0; r < 4; ++r) {
        int gm = m0 + wr * 64 + mi * 16 + rg + r;
        size_t off = (size_t)gm * N + gn;
        float v = acc[mi][ni][r] + bvv;
        if (EPI == 0) {
          ((u16*)Cout)[off] = f2bf(v);
        } else if (EPI == 1) {
          ((float*)Cout)[off] = v + resid[off];
        } else if (EPI == 2) {
          ((u16*)Cout)[off] = f2bf(gelu_fast(v));
        } else {
          int key = gm & 2047, bb = gm >> 11;
          if (gn < 512) {
            ((u16*)Cout)[off] = f2bf(v * QSCALE);
          } else if (gn < 1024) {
            ((u16*)Cout)[off] = f2bf(v);
          } else {
            int d = gn - 1024;             // h*64 + dim
            int kin = key & 63;
            int pc = (key & ~63) +
                     (((kin >> 5) << 5) | (((kin >> 2) & 3) << 3) | (((kin >> 4) & 1) << 2) | (kin & 3));
            vTout[((size_t)(bb * 8 + (d >> 6)) * 64 + (d & 63)) * 2048 + pc] = f2bf(v);
          }
        }
      }
    }
  }
}

// ---------------- GEMM narrow-N (BM=128, BN=64, BK=64, DOUBLE-BUFFERED) ----------------
// EPI 1 only: + resid(f32) -> f32. Top-of-loop prefetch; one barrier per K-iter.
__global__ __launch_bounds__(256) void gemm_n64_k(const u16* __restrict__ A, const u16* __restrict__ Bw,
                                                  const float* __restrict__ bias,
                                                  const float* __restrict__ resid,
                                                  float* __restrict__ Cout,
                                                  int M, int N, int K) {
  __shared__ u16 lA[2][128 * 64];
  __shared__ u16 lB[2][64 * 64];
  int t = threadIdx.x, w = t >> 6, l = t & 63;
  int orig = blockIdx.y * gridDim.x + blockIdx.x;
  int cpx = (gridDim.x * gridDim.y) >> 3;
  int swz = (orig & 7) * cpx + (orig >> 3);
  int m0 = (swz / gridDim.x) * 128, n0 = (swz % gridDim.x) * 64;
  int wr = w >> 1, wc = w & 1;          // waves: 2 in M (64 rows each) x 2 in N (32 cols each)
  int rl = l & 15, hi = l >> 4;
  f32x4 zero = {0.f, 0.f, 0.f, 0.f};
  f32x4 acc[4][2];
  #pragma unroll
  for (int mi = 0; mi < 4; ++mi)
    #pragma unroll
    for (int ni = 0; ni < 2; ++ni) acc[mi][ni] = zero;

  // stage tile 0
  #pragma unroll
  for (int it = 0; it < 4; ++it) {
    int cid = it * 256 + t;
    int row = cid >> 3, g = cid & 7;
    int gs = (g ^ (row & 7)) * 8;
    gload_lds16(A + (size_t)(m0 + row) * K + gs, &lA[0][(size_t)cid * 8]);
  }
  #pragma unroll
  for (int it = 0; it < 2; ++it) {
    int cid = it * 256 + t;
    int row = cid >> 3, g = cid & 7;
    int gs = (g ^ (row & 7)) * 8;
    gload_lds16(Bw + (size_t)(n0 + row) * K + gs, &lB[0][(size_t)cid * 8]);
  }
  __syncthreads();
  int nk = K >> 6;
  for (int kt = 0; kt < nk; ++kt) {
    int cur = kt & 1;
    // prefetch next K-tile first (buf[cur^1] free since previous barrier)
    if (kt + 1 < nk) {
      int k0 = (kt + 1) << 6;
      #pragma unroll
      for (int it = 0; it < 4; ++it) {
        int cid = it * 256 + t;
        int row = cid >> 3, g = cid & 7;
        int gs = (g ^ (row & 7)) * 8;
        gload_lds16(A + (size_t)(m0 + row) * K + k0 + gs, &lA[cur ^ 1][(size_t)cid * 8]);
      }
      #pragma unroll
      for (int it = 0; it < 2; ++it) {
        int cid = it * 256 + t;
        int row = cid >> 3, g = cid & 7;
        int gs = (g ^ (row & 7)) * 8;
        gload_lds16(Bw + (size_t)(n0 + row) * K + k0 + gs, &lB[cur ^ 1][(size_t)cid * 8]);
      }
    }
    #pragma unroll
    for (int kk = 0; kk < 2; ++kk) {
      bf16x8 af[4], bfr[2];
      #pragma unroll
      for (int mi = 0; mi < 4; ++mi) {
        int row = wr * 64 + mi * 16 + rl;
        af[mi] = *reinterpret_cast<const bf16x8*>(&lA[cur][row * 64 + (((kk * 4 + hi) ^ (row & 7)) * 8)]);
      }
      #pragma unroll
      for (int ni = 0; ni < 2; ++ni) {
        int row = wc * 32 + ni * 16 + rl;
        bfr[ni] = *reinterpret_cast<const bf16x8*>(&lB[cur][row * 64 + (((kk * 4 + hi) ^ (row & 7)) * 8)]);
      }
      #pragma unroll
      for (int mi = 0; mi < 4; ++mi)
        #pragma unroll
        for (int ni = 0; ni < 2; ++ni) acc[mi][ni] = MFMA(af[mi], bfr[ni], acc[mi][ni]);
    }
    __syncthreads();   // drains prefetch + protects buffer reuse
  }
  int rg = hi * 4;
  #pragma unroll
  for (int mi = 0; mi < 4; ++mi) {
    #pragma unroll
    for (int ni = 0; ni < 2; ++ni) {
      int gn = n0 + wc * 32 + ni * 16 + rl;
      float bvv = bias[gn];
      #pragma unroll
      for (int r = 0; r < 4; ++r) {
        int gm = m0 + wr * 64 + mi * 16 + rg + r;
        size_t off = (size_t)gm * N + gn;
        Cout[off] = acc[mi][ni][r] + bvv + resid[off];
      }
    }
  }
}

// ---------------- Fused flash ctx v8: swapped QK^T, P fully in registers ----------------
__global__ __launch_bounds__(512) void attn_fctx8_k(const u16* __restrict__ qkv,
                                                    const u16* __restrict__ vT,
                                                    float* __restrict__ rinv,
                                                    u16* __restrict__ ctx) {
  __shared__ u16 kbuf[2][64 * 64];
  __shared__ u16 vbuf[2][64 * 64];
  int t = threadIdx.x, w = t >> 6, l = t & 63;
  // HW linear id (x fastest); xcd = n&7. Group (b,h): 32 groups x 16 q-blocks.
  int n = blockIdx.x + 16 * (blockIdx.y + 8 * blockIdx.z);
  int slot = n >> 3;
  int g = (n & 7) * 4 + (slot >> 4);
  int qb = slot & 15;
  int h = g >> 2, b = g & 3;
  int qt = qb * 128 + w * 16;
  int rl = l & 15, hi = l >> 4;
  f32x4 zero = {0.f, 0.f, 0.f, 0.f};
  // Q as B-frag: lane (hi,rl) holds Q[q=rl][d = hi*8+e] (+32 for second half)
  bf16x8 q0 = *reinterpret_cast<const bf16x8*>(
      qkv + (size_t)(b * S_ + qt + rl) * 1536 + h * 64 + hi * 8);
  bf16x8 q1 = *reinterpret_cast<const bf16x8*>(
      qkv + (size_t)(b * S_ + qt + rl) * 1536 + h * 64 + 32 + hi * 8);
  f32x4 acc[4];
  float lspq = 0.f;   // per-lane partial row-sum for q = rl
  #pragma unroll
  for (int dc = 0; dc < 4; ++dc) acc[dc] = zero;
  // stage tile 0 (512 threads x 16B cover each 8KB tile)
  {
    int r = t >> 3, gp = t & 7, gl = gp ^ (r & 7);
    gload_lds16(qkv + (size_t)(b * S_ + r) * 1536 + 512 + h * 64 + gl * 8, &kbuf[0][t * 8]);
    gload_lds16(vT + ((size_t)(b * H_ + h) * 64 + r) * 2048 + gl * 8, &vbuf[0][t * 8]);
  }
  __syncthreads();
  for (int kt = 0; kt < 32; ++kt) {
    int cur = kt & 1;
    if (kt + 1 < 32) {
      int r = t >> 3, gp = t & 7, gl = gp ^ (r & 7);
      gload_lds16(qkv + (size_t)(b * S_ + (kt + 1) * 64 + r) * 1536 + 512 + h * 64 + gl * 8,
                  &kbuf[cur ^ 1][t * 8]);
      gload_lds16(vT + ((size_t)(b * H_ + h) * 64 + r) * 2048 + (kt + 1) * 64 + gl * 8,
                  &vbuf[cur ^ 1][t * 8]);
    }
    const u16* kb = kbuf[cur];
    const u16* vb = vbuf[cur];
    // QK^T swapped: lane holds S[key=j*16+hi*4+r][q=rl]
    f32x4 s[4];
    __builtin_amdgcn_s_setprio(1);
    #pragma unroll
    for (int j = 0; j < 4; ++j) {
      int row = j * 16 + rl;
      bf16x8 k0 = *reinterpret_cast<const bf16x8*>(kb + row * 64 + ((hi ^ (row & 7)) * 8));
      bf16x8 k1 = *reinterpret_cast<const bf16x8*>(kb + row * 64 + (((hi + 4) ^ (row & 7)) * 8));
      s[j] = MFMA(k0, q0, zero);
      s[j] = MFMA(k1, q1, s[j]);
    }
    __builtin_amdgcn_s_setprio(0);
    // p = exp2(s); build PA frags in-register (k-slot order matches vT permutation)
    float p[4][4];
    #pragma unroll
    for (int j = 0; j < 4; ++j)
      #pragma unroll
      for (int r = 0; r < 4; ++r) {
        p[j][r] = hexp2(s[j][r]);
        lspq += p[j][r];
      }
    union { unsigned u[4]; bf16x8 v; } pa0, pa1;
    pa0.u[0] = cvtpk(p[0][0], p[0][1]); pa0.u[1] = cvtpk(p[0][2], p[0][3]);
    pa0.u[2] = cvtpk(p[1][0], p[1][1]); pa0.u[3] = cvtpk(p[1][2], p[1][3]);
    pa1.u[0] = cvtpk(p[2][0], p[2][1]); pa1.u[1] = cvtpk(p[2][2], p[2][3]);
    pa1.u[2] = cvtpk(p[3][0], p[3][1]); pa1.u[3] = cvtpk(p[3][2], p[3][3]);
    // PV: register A-operand
    __builtin_amdgcn_s_setprio(1);
    #pragma unroll
    for (int dc = 0; dc < 4; ++dc) {
      int row = dc * 16 + rl;
      bf16x8 v0 = *reinterpret_cast<const bf16x8*>(vb + row * 64 + ((hi ^ (row & 7)) * 8));
      bf16x8 v1 = *reinterpret_cast<const bf16x8*>(vb + row * 64 + (((hi + 4) ^ (row & 7)) * 8));
      acc[dc] = MFMA(pa0.v, v0, acc[dc]);
      acc[dc] = MFMA(pa1.v, v1, acc[dc]);
    }
    __builtin_amdgcn_s_setprio(0);
    __syncthreads();
  }
  // finish row sums: reduce over the 4 hi-groups
  lspq += __shfl_xor(lspq, 16);
  lspq += __shfl_xor(lspq, 32);
  float lr[4];
  #pragma unroll
  for (int r = 0; r < 4; ++r) lr[r] = __shfl(lspq, hi * 4 + r);
  #pragma unroll
  for (int dc = 0; dc < 4; ++dc)
    #pragma unroll
    for (int r = 0; r < 4; ++r)
      ctx[(size_t)(b * S_ + qt + hi * 4 + r) * 512 + h * 64 + dc * 16 + rl] =
          f2bf(acc[dc][r] / lr[r]);
  if (l < 16)
    rinv[(size_t)(b * H_ + h) * S_ + qt + rl] = 0.125f / lspq;
}

// ---------------- head-mean probs v10: dbuf heads, TOP-of-loop prefetch (linear IDs) ----------------
__global__ __launch_bounds__(256) void attn_mean10_k(const u16* __restrict__ qkv,
                                                     const float* __restrict__ rinv,
                                                     float* __restrict__ attn) {
  __shared__ u16 lQ[2][128 * 64];
  __shared__ u16 lK[2][128 * 64];
  int t = threadIdx.x, w = t >> 6, l = t & 63;
  int kt = blockIdx.x, qt = blockIdx.y, b = blockIdx.z;
  int wr = w >> 1, wc = w & 1;
  int rl = l & 15, hi = l >> 4;
  f32x4 zero = {0.f, 0.f, 0.f, 0.f};
  f32x4 acc[4][4];
  #pragma unroll
  for (int mi = 0; mi < 4; ++mi)
    #pragma unroll
    for (int ni = 0; ni < 4; ++ni) acc[mi][ni] = zero;

  const u16* qbase = qkv + (size_t)(b * S_ + qt * 128) * 1536;
  const u16* kbase = qkv + (size_t)(b * S_ + kt * 128) * 1536 + 512;
  // stage head 0 into buffer 0
  #pragma unroll
  for (int it = 0; it < 4; ++it) {
    int cid = it * 256 + t;
    int row = cid >> 3, g = cid & 7;
    int gs = (g ^ (row & 7)) * 8;
    gload_lds16(qbase + (size_t)row * 1536 + gs, &lQ[0][cid * 8]);
    gload_lds16(kbase + (size_t)row * 1536 + gs, &lK[0][cid * 8]);
  }
  __syncthreads();
  for (int h = 0; h < 8; ++h) {
    int cur = h & 1;
    // issue next head's staging FIRST (buf[cur^1] free since previous barrier)
    if (h + 1 < 8) {
      #pragma unroll
      for (int it = 0; it < 4; ++it) {
        int cid = it * 256 + t;
        int row = cid >> 3, g = cid & 7;
        int gs = (g ^ (row & 7)) * 8;
        gload_lds16(qbase + (size_t)row * 1536 + (h + 1) * 64 + gs, &lQ[cur ^ 1][cid * 8]);
        gload_lds16(kbase + (size_t)row * 1536 + (h + 1) * 64 + gs, &lK[cur ^ 1][cid * 8]);
      }
    }
    float4 rv[4];
    #pragma unroll
    for (int mi = 0; mi < 4; ++mi)
      rv[mi] = *reinterpret_cast<const float4*>(
          rinv + (size_t)(b * H_ + h) * S_ + qt * 128 + wr * 64 + mi * 16 + hi * 4);
    f32x4 s[4][4];
    __builtin_amdgcn_s_setprio(1);
    #pragma unroll
    for (int kk = 0; kk < 2; ++kk) {
      bf16x8 af[4], bfr[4];
      #pragma unroll
      for (int mi = 0; mi < 4; ++mi) {
        int row = wr * 64 + mi * 16 + rl;
        af[mi] = *reinterpret_cast<const bf16x8*>(&lQ[cur][row * 64 + (((kk * 4 + hi) ^ (row & 7)) * 8)]);
      }
      #pragma unroll
      for (int ni = 0; ni < 4; ++ni) {
        int row = wc * 64 + ni * 16 + rl;
        bfr[ni] = *reinterpret_cast<const bf16x8*>(&lK[cur][row * 64 + (((kk * 4 + hi) ^ (row & 7)) * 8)]);
      }
      #pragma unroll
      for (int mi = 0; mi < 4; ++mi)
        #pragma unroll
        for (int ni = 0; ni < 4; ++ni)
          s[mi][ni] = (kk == 0) ? MFMA(af[mi], bfr[ni], zero) : MFMA(af[mi], bfr[ni], s[mi][ni]);
    }
    __builtin_amdgcn_s_setprio(0);
    #pragma unroll
    for (int mi = 0; mi < 4; ++mi) {
      float rva[4] = {rv[mi].x, rv[mi].y, rv[mi].z, rv[mi].w};
      #pragma unroll
      for (int ni = 0; ni < 4; ++ni)
        #pragma unroll
        for (int r = 0; r < 4; ++r)
          acc[mi][ni][r] += hexp2(s[mi][ni][r]) * rva[r];
    }
    __syncthreads();   // drains prefetch vmcnt; protects buffer reuse
  }
  #pragma unroll
  for (int mi = 0; mi < 4; ++mi)
    #pragma unroll
    for (int r = 0; r < 4; ++r) {
      size_t rowoff = (size_t)(b * S_ + qt * 128 + wr * 64 + mi * 16 + hi * 4 + r) * 2048 +
                      kt * 128 + wc * 64 + rl;
      #pragma unroll
      for (int ni = 0; ni < 4; ++ni)
        attn[rowoff + ni * 16] = acc[mi][ni][r];
    }
}

// ---------------- launcher ----------------
extern "C" void kernel_launch(void* const* d_in, const int* in_sizes, int n_in,
                              void* d_out, int out_size, void* d_ws, size_t ws_size,
                              hipStream_t stream) {
  const float* query     = (const float*)d_in[0];
  const float* ln1_g     = (const float*)d_in[1];
  const float* ln1_b     = (const float*)d_in[2];
  const float* in_proj_w = (const float*)d_in[3];
  const float* in_proj_b = (const float*)d_in[4];
  const float* out_w     = (const float*)d_in[5];
  const float* out_b     = (const float*)d_in[6];
  const float* ln2_g     = (const float*)d_in[7];
  const float* ln2_b     = (const float*)d_in[8];
  const float* w1        = (const float*)d_in[9];
  const float* b1        = (const float*)d_in[10];
  const float* w2        = (const float*)d_in[11];
  const float* b2        = (const float*)d_in[12];

  u16* ws = (u16*)d_ws;
  u16* wq_bf = ws;                       // [1536,512]
  u16* wo_bf = wq_bf + 1536 * 512;       // [512,512]
  u16* w1_bf = wo_bf + 512 * 512;        // [2048,512]
  u16* w2_bf = w1_bf + 2048 * 512;       // [512,2048]
  u16* xq_bf = w2_bf + 512 * 2048;       // [8192,512]
  u16* qkv_bf = xq_bf + 8192 * 512;      // [8192,1536] (V section unused)
  u16* ctx_bf = qkv_bf + 8192 * 1536;    // [8192,512]
  u16* h_bf   = ctx_bf + 8192 * 512;     // [8192,512]
  u16* mh_bf  = h_bf + 8192 * 512;       // [8192,2048]
  float* rinv = (float*)(mh_bf + 8192 * 2048);  // [B*H*S]
  u16* vT = mh_bf;                       // [4,8,64,2048] alias (mh dead until MLP1)

  float* xout = (float*)d_out;                    // [8192,512]
  float* attn = xout + (size_t)8192 * 512;        // [4,2048,2048]

  // 1. weights -> bf16 + LN1 (single fused launch)
  prep_k<<<5120, 256, 0, stream>>>(in_proj_w, wq_bf, out_w, wo_bf, w1, w1_bf, w2, w2_bf,
                                   query, ln1_g, ln1_b, xq_bf);

  // 2. QKV projection (Q pre-scaled by log2e/8; V transposed+PA-permuted to vT)
  gemm_nt<3><<<dim3(12, 64), 256, 0, stream>>>(xq_bf, wq_bf, in_proj_b, nullptr, qkv_bf, vT, 8192, 1536, 512);

  // 3. fused flash ctx (swapped QK^T, register P, XCD-affinity remap)
  attn_fctx8_k<<<dim3(16, 8, 4), 512, 0, stream>>>(qkv_bf, vT, rinv, ctx_bf);

  // 4. head-mean probs -> attn_weight output (dbuf heads, linear IDs)
  attn_mean10_k<<<dim3(16, 16, 4), 256, 0, stream>>>(qkv_bf, rinv, attn);

  // 5. out-proj + residual(query) -> x (f32, d_out)  [BN=64, dbuf]
  gemm_n64_k<<<dim3(8, 64), 256, 0, stream>>>(ctx_bf, wo_bf, out_b, query, xout, 8192, 512, 512);

  // 6. LN2 on x
  ln_k<<<2048, 256, 0, stream>>>(xout, ln2_g, ln2_b, h_bf);

  // 7. MLP up + GELU (tanh-form via hw exp2)
  gemm_nt<2><<<dim3(16, 64), 256, 0, stream>>>(h_bf, w1_bf, b1, nullptr, mh_bf, nullptr, 8192, 2048, 512);

  // 8. MLP down + residual(x) -> final x (in-place)  [BN=64, dbuf]
  gemm_n64_k<<<dim3(8, 64), 256, 0, stream>>>(mh_bf, w2_bf, b2, xout, xout, 8192, 512, 2048);
}